// Round 1
// baseline (1749.385 us; speedup 1.0000x reference)
//
#include <hip/hip_runtime.h>
#include <hip/hip_bf16.h>

// Problem constants
#define Bb 8
#define Ls 2500
#define Dd 512
#define Yy 8921
#define LP 2560   // L padded to 20*128 (also multiple of BK=32)
#define YP 8960   // Y padded to 70*128

typedef short bf8 __attribute__((ext_vector_type(8)));   // 8 bf16 = 4 VGPRs (A/B frag)
typedef float f4  __attribute__((ext_vector_type(4)));   // C/D frag

// ---- workspace layout (bytes) ----
// rowsum : B*YP f32            @ 0          (286,720)
// ypart  : B*YP f32            @ 286,720    (286,720)
// lossacc: 1 f32               @ 573,440
// xb     : B*Ls*Dd bf16        @ 573,504    (20,480,000)
// xt     : B*Dd*LP bf16        @ 21,053,504 (20,971,520)
// Ub     : Yy*Dd bf16          @ 42,025,024 (9,135,104)
// pn     : B*YP*LP bf16        @ 51,160,128 (367,001,600)  -> total ~418.2 MB
#define OFF_ROWSUM  0
#define OFF_YPART   286720
#define OFF_LOSS    573440
#define OFF_XB      573504
#define OFF_XT      21053504
#define OFF_UB      42025024
#define OFF_PN      51160128

__device__ __forceinline__ void async16(const void* g, void* l) {
  __builtin_amdgcn_global_load_lds(
      (const __attribute__((address_space(1))) void*)g,
      (__attribute__((address_space(3))) void*)l, 16, 0, 0);
}

__device__ __forceinline__ unsigned short f2b(float f) {
  __hip_bfloat16 h = __float2bfloat16(f);
  unsigned short u;
  __builtin_memcpy(&u, &h, 2);
  return u;
}

// ---------------- pass 0: zero scratch accumulators ----------------
__global__ void zerok(float* p, int n) {
  int i = blockIdx.x * 256 + threadIdx.x;
  if (i < n) p[i] = 0.f;
}

// ---------------- pass 0: fp32 -> bf16 (vectorized) ----------------
__global__ void conv_bf16(const float4* __restrict__ src, ushort4* __restrict__ dst, int n4) {
  int i = blockIdx.x * 256 + threadIdx.x;
  if (i < n4) {
    float4 v = src[i];
    ushort4 o;
    o.x = f2b(v.x); o.y = f2b(v.y); o.z = f2b(v.z); o.w = f2b(v.w);
    dst[i] = o;
  }
}

// ---------------- pass 0: transpose x -> xt[b][d][LP] bf16, zero-pad l ----------------
__global__ __launch_bounds__(256) void transpose_x(const float* __restrict__ x,
                                                   __hip_bfloat16* __restrict__ xt) {
  __shared__ float tile[32][33];
  int lt = blockIdx.x;          // 0..79
  int dt = blockIdx.y;          // 0..15
  int b  = blockIdx.z;
  int l0 = lt * 32, d0 = dt * 32;
  int tx = threadIdx.x & 31, ty = threadIdx.x >> 5;   // 32 x 8
#pragma unroll
  for (int rr = 0; rr < 4; rr++) {
    int l = l0 + ty + rr * 8;
    float v = 0.f;
    if (l < Ls) v = x[((size_t)b * Ls + l) * Dd + d0 + tx];
    tile[ty + rr * 8][tx] = v;
  }
  __syncthreads();
#pragma unroll
  for (int rr = 0; rr < 4; rr++) {
    int d = d0 + ty + rr * 8;
    int l = l0 + tx;
    xt[((size_t)b * Dd + d) * LP + l] = __float2bfloat16(tile[tx][ty + rr * 8]);
  }
}

// ---------------- pass 1: scores GEMM + exp + rowsum ----------------
// C[y][l] = sum_d U[y][d]*x[l][d]; p=exp(C); pn bf16 (0 for l>=Ls); rowsum += p
__global__ __launch_bounds__(256) void gemm1(const __hip_bfloat16* __restrict__ Ub,
                                             const __hip_bfloat16* __restrict__ xb,
                                             __hip_bfloat16* __restrict__ pn,
                                             float* __restrict__ rowsum) {
  __shared__ __hip_bfloat16 As[128 * 32];
  __shared__ __hip_bfloat16 Bs[128 * 32];
  const int tid = threadIdx.x;
  const int lane = tid & 63, wid = tid >> 6;
  const int wm = wid >> 1, wn = wid & 1;
  const int lt = blockIdx.x, yt = blockIdx.y, b = blockIdx.z;
  const int y0 = yt * 128, l0 = lt * 128;

  f4 acc[4][4];
#pragma unroll
  for (int i = 0; i < 4; i++)
#pragma unroll
    for (int j = 0; j < 4; j++) acc[i][j] = (f4){0.f, 0.f, 0.f, 0.f};

  const __hip_bfloat16* Bbase = xb + (size_t)b * Ls * Dd;
  const int ml = lane & 15, kh = lane >> 4;

  for (int k0 = 0; k0 < Dd; k0 += 32) {
#pragma unroll
    for (int u = 0; u < 2; u++) {
      int c = tid + u * 256;
      int r = c >> 2, ko = (c & 3) * 8;
      int row = y0 + r; if (row > Yy - 1) row = Yy - 1;
      async16(Ub + (size_t)row * Dd + k0 + ko, &As[c * 8]);
    }
#pragma unroll
    for (int u = 0; u < 2; u++) {
      int c = tid + u * 256;
      int r = c >> 2, ko = (c & 3) * 8;
      int row = l0 + r; if (row > Ls - 1) row = Ls - 1;
      async16(Bbase + (size_t)row * Dd + k0 + ko, &Bs[c * 8]);
    }
    __syncthreads();
    bf8 a[4], bv[4];
#pragma unroll
    for (int i = 0; i < 4; i++)
      a[i] = *(const bf8*)&As[(wm * 64 + i * 16 + ml) * 32 + kh * 8];
#pragma unroll
    for (int j = 0; j < 4; j++)
      bv[j] = *(const bf8*)&Bs[(wn * 64 + j * 16 + ml) * 32 + kh * 8];
#pragma unroll
    for (int i = 0; i < 4; i++)
#pragma unroll
      for (int j = 0; j < 4; j++)
        acc[i][j] = __builtin_amdgcn_mfma_f32_16x16x32_bf16(a[i], bv[j], acc[i][j], 0, 0, 0);
    __syncthreads();
  }

  // epilogue: exp, store pn bf16, accumulate rowsum
  // C/D map: col = lane&15, row = (lane>>4)*4 + reg
#pragma unroll
  for (int i = 0; i < 4; i++) {
    float rs[4] = {0.f, 0.f, 0.f, 0.f};
#pragma unroll
    for (int j = 0; j < 4; j++) {
      int l = l0 + wn * 64 + j * 16 + ml;
      bool lv = (l < Ls);
#pragma unroll
      for (int r = 0; r < 4; r++) {
        int y = y0 + wm * 64 + i * 16 + kh * 4 + r;
        float p = __expf(acc[i][j][r]);
        if (!lv) p = 0.f;
        pn[((size_t)b * YP + y) * LP + l] = __float2bfloat16(p);
        rs[r] += p;
      }
    }
#pragma unroll
    for (int r = 0; r < 4; r++) {
      float v = rs[r];
      v += __shfl_xor(v, 1); v += __shfl_xor(v, 2);
      v += __shfl_xor(v, 4); v += __shfl_xor(v, 8);
      if (ml == 0) {
        int y = y0 + wm * 64 + i * 16 + kh * 4 + r;
        atomicAdd(&rowsum[(size_t)b * YP + y], v);
      }
    }
  }
}

// ---------------- pass 2: m GEMM (+ scale by 1/rowsum, + y-partial) ----------------
// C[y][d] = sum_l pn[y][l]*xt[d][l]; m = C/rowsum; ypart += sum_d fw[y][d]*m[y][d]
__global__ __launch_bounds__(256) void gemm2(const __hip_bfloat16* __restrict__ pn,
                                             const __hip_bfloat16* __restrict__ xt,
                                             const float* __restrict__ rowsum,
                                             const float* __restrict__ fw,
                                             float* __restrict__ mout,
                                             float* __restrict__ ypart) {
  __shared__ __hip_bfloat16 As[128 * 32];
  __shared__ __hip_bfloat16 Bs[128 * 32];
  const int tid = threadIdx.x;
  const int lane = tid & 63, wid = tid >> 6;
  const int wm = wid >> 1, wn = wid & 1;
  const int dt = blockIdx.x, yt = blockIdx.y, b = blockIdx.z;
  const int y0 = yt * 128, d0 = dt * 128;

  f4 acc[4][4];
#pragma unroll
  for (int i = 0; i < 4; i++)
#pragma unroll
    for (int j = 0; j < 4; j++) acc[i][j] = (f4){0.f, 0.f, 0.f, 0.f};

  const __hip_bfloat16* Abase = pn + (size_t)b * YP * LP;
  const __hip_bfloat16* Bbase = xt + (size_t)b * Dd * LP;
  const int ml = lane & 15, kh = lane >> 4;

  for (int k0 = 0; k0 < LP; k0 += 32) {
#pragma unroll
    for (int u = 0; u < 2; u++) {
      int c = tid + u * 256;
      int r = c >> 2, ko = (c & 3) * 8;
      async16(Abase + (size_t)(y0 + r) * LP + k0 + ko, &As[c * 8]);
    }
#pragma unroll
    for (int u = 0; u < 2; u++) {
      int c = tid + u * 256;
      int r = c >> 2, ko = (c & 3) * 8;
      async16(Bbase + (size_t)(d0 + r) * LP + k0 + ko, &Bs[c * 8]);
    }
    __syncthreads();
    bf8 a[4], bv[4];
#pragma unroll
    for (int i = 0; i < 4; i++)
      a[i] = *(const bf8*)&As[(wm * 64 + i * 16 + ml) * 32 + kh * 8];
#pragma unroll
    for (int j = 0; j < 4; j++)
      bv[j] = *(const bf8*)&Bs[(wn * 64 + j * 16 + ml) * 32 + kh * 8];
#pragma unroll
    for (int i = 0; i < 4; i++)
#pragma unroll
      for (int j = 0; j < 4; j++)
        acc[i][j] = __builtin_amdgcn_mfma_f32_16x16x32_bf16(a[i], bv[j], acc[i][j], 0, 0, 0);
    __syncthreads();
  }

#pragma unroll
  for (int i = 0; i < 4; i++) {
#pragma unroll
    for (int r = 0; r < 4; r++) {
      int y = y0 + wm * 64 + i * 16 + kh * 4 + r;
      float inv = 1.f / rowsum[(size_t)b * YP + y];
      int yc = y < Yy ? y : Yy - 1;
      float dotp = 0.f;
#pragma unroll
      for (int j = 0; j < 4; j++) {
        int d = d0 + wn * 64 + j * 16 + ml;
        float mv = acc[i][j][r] * inv;
        if (y < Yy) mout[((size_t)b * Yy + y) * Dd + d] = mv;
        dotp += mv * fw[(size_t)yc * Dd + d];
      }
      float v = dotp;
      v += __shfl_xor(v, 1); v += __shfl_xor(v, 2);
      v += __shfl_xor(v, 4); v += __shfl_xor(v, 8);
      if (ml == 0) atomicAdd(&ypart[(size_t)b * YP + y], v);
    }
  }
}

// ---------------- pass 3: alpha = pn / rowsum (fp32 out) ----------------
__global__ __launch_bounds__(256) void alpha_norm(const __hip_bfloat16* __restrict__ pn,
                                                  const float* __restrict__ rowsum,
                                                  float* __restrict__ alpha) {
  int row = blockIdx.x;               // 0..B*Yy-1
  int b = row / Yy;
  int y = row - b * Yy;
  float inv = 1.f / rowsum[(size_t)b * YP + y];
  const __hip_bfloat16* src = pn + ((size_t)b * YP + y) * LP;
  float* dst = alpha + (size_t)row * Ls;
  for (int l = threadIdx.x; l < Ls; l += 256)
    dst[l] = __bfloat162float(src[l]) * inv;
}

// ---------------- pass 4: y = ypart + bias; BCE partial reduce ----------------
__global__ __launch_bounds__(256) void ybce(const float* __restrict__ ypart,
                                            const float* __restrict__ fb,
                                            const float* __restrict__ tgt,
                                            float* __restrict__ yout,
                                            float* __restrict__ lacc) {
  int idx = blockIdx.x * 256 + threadIdx.x;
  float term = 0.f;
  if (idx < Bb * Yy) {
    int b = idx / Yy, yy = idx - b * Yy;
    float v = ypart[(size_t)b * YP + yy] + fb[yy];
    yout[idx] = v;
    float t = tgt[idx];
    term = fmaxf(v, 0.f) - v * t + log1pf(__expf(-fabsf(v)));
  }
  term += __shfl_down(term, 32);
  term += __shfl_down(term, 16);
  term += __shfl_down(term, 8);
  term += __shfl_down(term, 4);
  term += __shfl_down(term, 2);
  term += __shfl_down(term, 1);
  __shared__ float red[4];
  int lane = threadIdx.x & 63, wid = threadIdx.x >> 6;
  if (lane == 0) red[wid] = term;
  __syncthreads();
  if (threadIdx.x == 0) atomicAdd(lacc, red[0] + red[1] + red[2] + red[3]);
}

__global__ void fin(const float* __restrict__ lacc, float* __restrict__ lout) {
  lout[0] = lacc[0] * (1.f / (float)(Bb * Yy));
}

extern "C" void kernel_launch(void* const* d_in, const int* in_sizes, int n_in,
                              void* d_out, int out_size, void* d_ws, size_t ws_size,
                              hipStream_t stream) {
  const float* x  = (const float*)d_in[0];
  const float* tg = (const float*)d_in[1];
  const float* Uw = (const float*)d_in[3];
  const float* fw = (const float*)d_in[4];
  const float* fb = (const float*)d_in[5];

  float* out   = (float*)d_out;
  float* yout  = out;
  float* lout  = out + (size_t)Bb * Yy;
  float* alpha = lout + 1;
  float* mout  = alpha + (size_t)Bb * Yy * Ls;

  char* ws = (char*)d_ws;
  float* rowsum = (float*)(ws + OFF_ROWSUM);
  float* ypart  = (float*)(ws + OFF_YPART);
  float* lacc   = (float*)(ws + OFF_LOSS);
  __hip_bfloat16* xb = (__hip_bfloat16*)(ws + OFF_XB);
  __hip_bfloat16* xt = (__hip_bfloat16*)(ws + OFF_XT);
  __hip_bfloat16* Ub = (__hip_bfloat16*)(ws + OFF_UB);
  __hip_bfloat16* pn = (__hip_bfloat16*)(ws + OFF_PN);

  // zero rowsum + ypart + lossacc
  int nz = 2 * Bb * YP + 1;
  zerok<<<(nz + 255) / 256, 256, 0, stream>>>(rowsum, nz);

  // conversions
  conv_bf16<<<(Bb * Ls * Dd / 4 + 255) / 256, 256, 0, stream>>>(
      (const float4*)x, (ushort4*)xb, Bb * Ls * Dd / 4);
  transpose_x<<<dim3(80, 16, Bb), 256, 0, stream>>>(x, xt);
  conv_bf16<<<(Yy * Dd / 4 + 255) / 256, 256, 0, stream>>>(
      (const float4*)Uw, (ushort4*)Ub, Yy * Dd / 4);

  // scores + exp + rowsum
  gemm1<<<dim3(LP / 128, YP / 128, Bb), 256, 0, stream>>>(Ub, xb, pn, rowsum);
  // m + y-partials
  gemm2<<<dim3(Dd / 128, YP / 128, Bb), 256, 0, stream>>>(pn, xt, rowsum, fw, mout, ypart);
  // alpha
  alpha_norm<<<Bb * Yy, 256, 0, stream>>>(pn, rowsum, alpha);
  // y + loss
  ybce<<<(Bb * Yy + 255) / 256, 256, 0, stream>>>(ypart, fb, tg, yout, lacc);
  fin<<<1, 1, 0, stream>>>(lacc, lout);
}